// Round 1
// baseline (3103.597 us; speedup 1.0000x reference)
//
#include <hip/hip_runtime.h>
#include <hip/hip_bf16.h>

// LightGCN_27384711480190
// Sizes fixed by the problem definition:
#define NUQ 100000   // users
#define NIQ 50000    // items
#define NQ  150000   // N = NU + NI
#define DQ  64       // embedding dim (== wavefront size, 1 lane per dim)
#define GQ  4        // groups

// ---------------------------------------------------------------------------
// side = spmm(vals, all_emb) accumulated in f64 (argmax-decision accuracy).
// One wave (64 lanes) per edge; lane = dim.
__global__ void spmm_side_f64(const float* __restrict__ vals,
                              const int* __restrict__ rows,
                              const int* __restrict__ cols,
                              const float* __restrict__ user_emb,
                              const float* __restrict__ item_emb,
                              double* __restrict__ side64, int nnz) {
    int wid  = (int)(((size_t)blockIdx.x * blockDim.x + threadIdx.x) >> 6);
    int lane = threadIdx.x & 63;
    if (wid >= nnz) return;
    int   r = rows[wid];
    int   c = cols[wid];
    float v = vals[wid];
    const float* src = (c < NUQ) ? (user_emb + (size_t)c * DQ)
                                 : (item_emb + (size_t)(c - NUQ) * DQ);
    double add = (double)v * (double)src[lane];
    unsafeAtomicAdd(side64 + (size_t)r * DQ + lane, add);
}

// ---------------------------------------------------------------------------
// Per-user: temp = leaky_relu((emb+side) @ fc_w + fc_b); scores = temp @ fcg_w
// + fcg_b; mask bit g set iff scores[g] == max(scores).  All in f64.
// One wave per user row; lane = dim.
__global__ void scores_mask_kernel(const float* __restrict__ user_emb,
                                   const double* __restrict__ side64,
                                   const float* __restrict__ fc_w,
                                   const float* __restrict__ fc_b,
                                   const float* __restrict__ fcg_w,
                                   const float* __restrict__ fcg_b,
                                   unsigned int* __restrict__ mask) {
    int wid  = (int)(((size_t)blockIdx.x * blockDim.x + threadIdx.x) >> 6);
    int lane = threadIdx.x & 63;
    if (wid >= NUQ) return;
    int row = wid;

    double x = (double)user_emb[(size_t)row * DQ + lane]
             + side64[(size_t)row * DQ + lane];

    // temp[lane] = fc_b[lane] + sum_k x[k] * fc_w[k][lane]
    double t = (double)fc_b[lane];
    #pragma unroll 16
    for (int k = 0; k < DQ; ++k) {
        double xk = __shfl(x, k, 64);
        t += xk * (double)fc_w[k * DQ + lane];
    }
    t = (t > 0.0) ? t : 0.01 * t;   // leaky_relu, slope 0.01

    // scores[g] = fcg_b[g] + sum_d t[d] * fcg_w[d][g]
    double s[GQ];
    #pragma unroll
    for (int g = 0; g < GQ; ++g) {
        double v = t * (double)fcg_w[lane * GQ + g];
        #pragma unroll
        for (int off = 32; off > 0; off >>= 1) v += __shfl_xor(v, off, 64);
        s[g] = v + (double)fcg_b[g];
    }
    double m = fmax(fmax(s[0], s[1]), fmax(s[2], s[3]));
    unsigned bits = 0;
    #pragma unroll
    for (int g = 0; g < GQ; ++g) if (s[g] == m) bits |= (1u << g);
    if (lane == 0) mask[row] = bits;
}

// Items belong to every group.
__global__ void item_mask_kernel(unsigned int* __restrict__ mask) {
    int i = blockIdx.x * blockDim.x + threadIdx.x;
    if (i < NIQ) mask[NUQ + i] = 0xFu;
}

// side32 = (float)side64 ; acc = G * side32   (layer-0 contribution)
__global__ void init_acc_kernel(const double* __restrict__ side64,
                                float* __restrict__ side32,
                                float* __restrict__ acc) {
    size_t i = (size_t)blockIdx.x * blockDim.x + threadIdx.x;
    if (i >= (size_t)NQ * DQ) return;
    float s = (float)side64[i];
    side32[i] = s;
    acc[i]    = (float)GQ * s;
}

// ---------------------------------------------------------------------------
// One masked-group SpMM pass: y[r] += v * x[c] for edges active in group g.
// Whole wave takes the same branch (edge-uniform) -> no divergence cost.
__global__ void spmm_group(const float* __restrict__ vals,
                           const int* __restrict__ rows,
                           const int* __restrict__ cols,
                           const unsigned int* __restrict__ mask, int g,
                           const float* __restrict__ x,
                           float* __restrict__ y, int nnz) {
    int wid  = (int)(((size_t)blockIdx.x * blockDim.x + threadIdx.x) >> 6);
    int lane = threadIdx.x & 63;
    if (wid >= nnz) return;
    int r = rows[wid];
    int c = cols[wid];
    if (!(((mask[r] >> g) & (mask[c] >> g)) & 1u)) return;
    float v = vals[wid];
    unsafeAtomicAdd(y + (size_t)r * DQ + lane, v * x[(size_t)c * DQ + lane]);
}

__global__ void acc_add_kernel(float* __restrict__ acc,
                               const float* __restrict__ emb) {
    size_t i = (size_t)blockIdx.x * blockDim.x + threadIdx.x;
    if (i < (size_t)NQ * DQ) acc[i] += emb[i];
}

// gamma[b] = 0.04 * dot(acc[users[b]], acc[NU + items[b]])   (0.2^2 = 0.04)
__global__ void gamma_kernel(const float* __restrict__ acc,
                             const int* __restrict__ users,
                             const int* __restrict__ items,
                             float* __restrict__ out, int B) {
    int wid  = (int)(((size_t)blockIdx.x * blockDim.x + threadIdx.x) >> 6);
    int lane = threadIdx.x & 63;
    if (wid >= B) return;
    int u  = users[wid];
    int it = items[wid];
    float a = acc[(size_t)u * DQ + lane];
    float b = acc[(size_t)(NUQ + it) * DQ + lane];
    float p = a * b;
    #pragma unroll
    for (int off = 32; off > 0; off >>= 1) p += __shfl_xor(p, off, 64);
    if (lane == 0) out[wid] = 0.04f * p;
}

// ---------------------------------------------------------------------------
extern "C" void kernel_launch(void* const* d_in, const int* in_sizes, int n_in,
                              void* d_out, int out_size, void* d_ws, size_t ws_size,
                              hipStream_t stream) {
    const float* user_emb = (const float*)d_in[0];
    const float* item_emb = (const float*)d_in[1];
    const float* fc_w     = (const float*)d_in[2];
    const float* fc_b     = (const float*)d_in[3];
    const float* fcg_w    = (const float*)d_in[4];
    const float* fcg_b    = (const float*)d_in[5];
    const float* vals     = (const float*)d_in[6];
    const int*   rows     = (const int*)d_in[7];
    const int*   cols     = (const int*)d_in[8];
    const int*   users    = (const int*)d_in[9];
    const int*   items    = (const int*)d_in[10];
    const int nnz = in_sizes[6];
    const int B   = in_sizes[9];
    float* out = (float*)d_out;

    const size_t ND = (size_t)NQ * DQ;   // 9,600,000
    // Workspace layout (all 256B aligned):
    char* ws = (char*)d_ws;
    double*       side64 = (double*)(ws);                    // 76,800,000 B
    float*        side32 = (float*)(ws + 76800000);          // 38,400,000 B
    float*        acc    = (float*)(ws + 115200000);         // 38,400,000 B
    float*        emb1   = (float*)(ws + 153600000);         // 38,400,000 B
    unsigned int* mask   = (unsigned int*)(ws + 192000000);  //    600,000 B

    hipMemsetAsync(side64, 0, ND * sizeof(double), stream);

    {   // side (f64)
        size_t thr = (size_t)nnz * 64;
        spmm_side_f64<<<(int)((thr + 255) / 256), 256, 0, stream>>>(
            vals, rows, cols, user_emb, item_emb, side64, nnz);
    }
    {   // user scores -> group masks (f64)
        size_t thr = (size_t)NUQ * 64;
        scores_mask_kernel<<<(int)((thr + 255) / 256), 256, 0, stream>>>(
            user_emb, side64, fc_w, fc_b, fcg_w, fcg_b, mask);
    }
    item_mask_kernel<<<(NIQ + 255) / 256, 256, 0, stream>>>(mask);
    init_acc_kernel<<<(int)((ND + 255) / 256), 256, 0, stream>>>(side64, side32, acc);

    const int spmm_blocks = (int)(((size_t)nnz * 64 + 255) / 256);
    for (int g = 0; g < GQ; ++g) {
        hipMemsetAsync(emb1, 0, ND * sizeof(float), stream);
        // layer 1: emb1 = spmm(vals_g, side)
        spmm_group<<<spmm_blocks, 256, 0, stream>>>(vals, rows, cols, mask, g,
                                                    side32, emb1, nnz);
        // acc += emb1
        acc_add_kernel<<<(int)((ND + 255) / 256), 256, 0, stream>>>(acc, emb1);
        // layer 2: acc += spmm(vals_g, emb1)   (accumulate directly into acc)
        spmm_group<<<spmm_blocks, 256, 0, stream>>>(vals, rows, cols, mask, g,
                                                    emb1, acc, nnz);
    }

    gamma_kernel<<<(int)(((size_t)B * 64 + 255) / 256), 256, 0, stream>>>(
        acc, users, items, out, B);
}

// Round 2
// 1005.674 us; speedup vs baseline: 3.0861x; 3.0861x over previous
//
#include <hip/hip_runtime.h>
#include <hip/hip_bf16.h>

// LightGCN_27384711480190 — CSR-based, atomic-free SpMM passes.
#define NUQ 100000   // users
#define NIQ 50000    // items
#define NQ  150000   // N = NU + NI
#define DQ  64       // embedding dim (== wavefront)
#define GQ  4        // groups

#define SCAN_NB  ((NQ + 255) / 256)          // 586 scan blocks
#define SCANB_PER ((SCAN_NB + 63) / 64)      // 10 elems per lane in scanB

// ---------------------------------------------------------------------------
// CSR build: histogram -> exclusive scan -> scatter (order within a row is
// nondeterministic but only perturbs f32 sums at ~1e-7; f64 score path is
// unaffected at argmax-decision level).
__global__ void hist_kernel(const int* __restrict__ rows, int* __restrict__ cnt,
                            int nnz) {
    int e = blockIdx.x * blockDim.x + threadIdx.x;
    if (e < nnz) atomicAdd(&cnt[rows[e]], 1);
}

__global__ void scanA_kernel(const int* __restrict__ cnt, int* __restrict__ ofs,
                             int* __restrict__ bsum, int n) {
    int i = blockIdx.x * 256 + threadIdx.x;
    int v = (i < n) ? cnt[i] : 0;
    int lane = threadIdx.x & 63, w = threadIdx.x >> 6;
    int s = v;
    #pragma unroll
    for (int off = 1; off < 64; off <<= 1) {
        int t = __shfl_up(s, off, 64);
        if (lane >= off) s += t;
    }
    __shared__ int wsum[4];
    if (lane == 63) wsum[w] = s;
    __syncthreads();
    int add = 0;
    for (int k = 0; k < w; ++k) add += wsum[k];
    int incl = s + add;
    if (i < n) ofs[i] = incl - v;          // exclusive prefix within block
    if (threadIdx.x == 255) bsum[blockIdx.x] = incl;  // block total
}

__global__ void scanB_kernel(int* __restrict__ bsum) {
    int lane = threadIdx.x;                 // single wave of 64
    int base = lane * SCANB_PER;
    int local[SCANB_PER];
    int s = 0;
    #pragma unroll
    for (int k = 0; k < SCANB_PER; ++k) {
        int idx = base + k;
        int t = (idx < SCAN_NB) ? bsum[idx] : 0;
        local[k] = s;                       // chunk-local exclusive prefix
        s += t;
    }
    int incl = s;
    #pragma unroll
    for (int off = 1; off < 64; off <<= 1) {
        int t = __shfl_up(incl, off, 64);
        if (lane >= off) incl += t;
    }
    int excl = incl - s;
    #pragma unroll
    for (int k = 0; k < SCANB_PER; ++k) {
        int idx = base + k;
        if (idx < SCAN_NB) bsum[idx] = excl + local[k];
    }
}

__global__ void scanC_kernel(int* __restrict__ ofs, const int* __restrict__ bsum,
                             int n, int nnz) {
    int i = blockIdx.x * 256 + threadIdx.x;
    if (i < n) ofs[i] += bsum[blockIdx.x];
    if (i == 0) ofs[n] = nnz;
}

__global__ void scatter_kernel(const int* __restrict__ rows,
                               const int* __restrict__ cols,
                               const float* __restrict__ vals,
                               const int* __restrict__ ofs,
                               int* __restrict__ fill,
                               uint2* __restrict__ edge_cv, int nnz) {
    int e = blockIdx.x * blockDim.x + threadIdx.x;
    if (e >= nnz) return;
    int r = rows[e];
    int pos = ofs[r] + atomicAdd(&fill[r], 1);
    edge_cv[pos] = make_uint2((unsigned)cols[e], __float_as_uint(vals[e]));
}

// ---------------------------------------------------------------------------
// Fused: side row (f64 register accumulation) + FC/leaky/FC_g/argmax mask.
// One wave per row; lane = dim. No atomics, one 256B store per row.
__global__ void side_scores_kernel(const float* __restrict__ user_emb,
                                   const float* __restrict__ item_emb,
                                   const float* __restrict__ fc_w,
                                   const float* __restrict__ fc_b,
                                   const float* __restrict__ fcg_w,
                                   const float* __restrict__ fcg_b,
                                   const int* __restrict__ ofs,
                                   const uint2* __restrict__ edge_cv,
                                   float* __restrict__ side32,
                                   unsigned int* __restrict__ mask) {
    int wid  = (int)(((size_t)blockIdx.x * blockDim.x + threadIdx.x) >> 6);
    int lane = threadIdx.x & 63;
    if (wid >= NQ) return;
    int r = wid;
    int beg = ofs[r], end = ofs[r + 1];
    double a = 0.0;
    for (int i = beg; i < end; ++i) {
        uint2 cv = edge_cv[i];
        int   c  = (int)cv.x;
        float v  = __uint_as_float(cv.y);
        const float* src = (c < NUQ) ? (user_emb + (size_t)c * DQ)
                                     : (item_emb + (size_t)(c - NUQ) * DQ);
        a += (double)v * (double)src[lane];
    }
    side32[(size_t)r * DQ + lane] = (float)a;

    if (r >= NUQ) {                       // items: all groups
        if (lane == 0) mask[r] = 0xFu;
        return;
    }
    // scores in f64 (argmax decision robustness vs np reference)
    double x = (double)user_emb[(size_t)r * DQ + lane] + a;
    double t = (double)fc_b[lane];
    #pragma unroll 16
    for (int k = 0; k < DQ; ++k) {
        double xk = __shfl(x, k, 64);
        t += xk * (double)fc_w[k * DQ + lane];
    }
    t = (t > 0.0) ? t : 0.01 * t;         // leaky_relu
    double s[GQ];
    #pragma unroll
    for (int g = 0; g < GQ; ++g) {
        double v2 = t * (double)fcg_w[lane * GQ + g];
        #pragma unroll
        for (int off = 32; off > 0; off >>= 1) v2 += __shfl_xor(v2, off, 64);
        s[g] = v2 + (double)fcg_b[g];
    }
    double m = fmax(fmax(s[0], s[1]), fmax(s[2], s[3]));
    unsigned bits = 0;
    #pragma unroll
    for (int g = 0; g < GQ; ++g) if (s[g] == m) bits |= (1u << g);
    if (lane == 0) mask[r] = bits;
}

// ---------------------------------------------------------------------------
// Layer 1 (all 4 groups in one pass; input side is group-independent):
// emb1_g[r] = sum_{e in row r, active g} v * side[c];  acc[r] = 4*side + sum_g.
__global__ void layer1_kernel(const int* __restrict__ ofs,
                              const uint2* __restrict__ edge_cv,
                              const unsigned int* __restrict__ mask,
                              const float* __restrict__ side32,
                              float* __restrict__ emb1,   // [4][N][64]
                              float* __restrict__ acc) {
    int wid  = (int)(((size_t)blockIdx.x * blockDim.x + threadIdx.x) >> 6);
    int lane = threadIdx.x & 63;
    if (wid >= NQ) return;
    int r = wid;
    unsigned mr = mask[r];
    int beg = ofs[r], end = ofs[r + 1];
    float a0 = 0.f, a1 = 0.f, a2 = 0.f, a3 = 0.f;
    for (int i = beg; i < end; ++i) {
        uint2 cv = edge_cv[i];
        int   c  = (int)cv.x;
        unsigned mb = mr & mask[c];
        if (!mb) continue;
        float v  = __uint_as_float(cv.y);
        float vs = v * side32[(size_t)c * DQ + lane];
        if (mb & 1u) a0 += vs;
        if (mb & 2u) a1 += vs;
        if (mb & 4u) a2 += vs;
        if (mb & 8u) a3 += vs;
    }
    const size_t ND = (size_t)NQ * DQ;
    size_t o = (size_t)r * DQ + lane;
    emb1[o]          = a0;
    emb1[ND + o]     = a1;
    emb1[2 * ND + o] = a2;
    emb1[3 * ND + o] = a3;
    acc[o] = 4.0f * side32[o] + (a0 + a1 + a2 + a3);
}

// Layer 2: acc[r] += sum_g sum_{e active g} v * emb1_g[c].
__global__ void layer2_kernel(const int* __restrict__ ofs,
                              const uint2* __restrict__ edge_cv,
                              const unsigned int* __restrict__ mask,
                              const float* __restrict__ emb1,  // [4][N][64]
                              float* __restrict__ acc) {
    int wid  = (int)(((size_t)blockIdx.x * blockDim.x + threadIdx.x) >> 6);
    int lane = threadIdx.x & 63;
    if (wid >= NQ) return;
    int r = wid;
    unsigned mr = mask[r];
    int beg = ofs[r], end = ofs[r + 1];
    const size_t ND = (size_t)NQ * DQ;
    float sum = 0.f;
    for (int i = beg; i < end; ++i) {
        uint2 cv = edge_cv[i];
        int   c  = (int)cv.x;
        unsigned mb = mr & mask[c];
        if (!mb) continue;
        float v = __uint_as_float(cv.y);
        size_t co = (size_t)c * DQ + lane;
        if (mb & 1u) sum += v * emb1[co];
        if (mb & 2u) sum += v * emb1[ND + co];
        if (mb & 4u) sum += v * emb1[2 * ND + co];
        if (mb & 8u) sum += v * emb1[3 * ND + co];
    }
    size_t o = (size_t)r * DQ + lane;
    acc[o] += sum;
}

// gamma[b] = 0.04 * dot(acc[users[b]], acc[NU + items[b]])   (0.2^2)
__global__ void gamma_kernel(const float* __restrict__ acc,
                             const int* __restrict__ users,
                             const int* __restrict__ items,
                             float* __restrict__ out, int B) {
    int wid  = (int)(((size_t)blockIdx.x * blockDim.x + threadIdx.x) >> 6);
    int lane = threadIdx.x & 63;
    if (wid >= B) return;
    int u  = users[wid];
    int it = items[wid];
    float a = acc[(size_t)u * DQ + lane];
    float b = acc[(size_t)(NUQ + it) * DQ + lane];
    float p = a * b;
    #pragma unroll
    for (int off = 32; off > 0; off >>= 1) p += __shfl_xor(p, off, 64);
    if (lane == 0) out[wid] = 0.04f * p;
}

// ---------------------------------------------------------------------------
extern "C" void kernel_launch(void* const* d_in, const int* in_sizes, int n_in,
                              void* d_out, int out_size, void* d_ws, size_t ws_size,
                              hipStream_t stream) {
    const float* user_emb = (const float*)d_in[0];
    const float* item_emb = (const float*)d_in[1];
    const float* fc_w     = (const float*)d_in[2];
    const float* fc_b     = (const float*)d_in[3];
    const float* fcg_w    = (const float*)d_in[4];
    const float* fcg_b    = (const float*)d_in[5];
    const float* vals     = (const float*)d_in[6];
    const int*   rows     = (const int*)d_in[7];
    const int*   cols     = (const int*)d_in[8];
    const int*   users    = (const int*)d_in[9];
    const int*   items    = (const int*)d_in[10];
    const int nnz = in_sizes[6];
    const int B   = in_sizes[9];
    float* out = (float*)d_out;

    const size_t ND = (size_t)NQ * DQ;           // 9.6M floats

    // Workspace layout (256B-aligned chunks):
    char* ws = (char*)d_ws;
    size_t off = 0;
    float* emb1 = (float*)(ws + off); off += 4 * ND * sizeof(float);   // 153.6 MB
    float* side32 = (float*)(ws + off); off += ND * sizeof(float);     //  38.4 MB
    float* acc    = (float*)(ws + off); off += ND * sizeof(float);     //  38.4 MB
    uint2* edge_cv = (uint2*)(ws + off); off += (size_t)nnz * 8;       //  16.0 MB
    int* row_ofs  = (int*)(ws + off); off += ((size_t)(NQ + 1) * 4 + 255) / 256 * 256;
    int* row_cnt  = (int*)(ws + off); off += ((size_t)NQ * 4 + 255) / 256 * 256;
    int* row_fill = (int*)(ws + off); off += ((size_t)NQ * 4 + 255) / 256 * 256;
    unsigned int* mask = (unsigned int*)(ws + off); off += ((size_t)NQ * 4 + 255) / 256 * 256;
    int* bsum     = (int*)(ws + off); off += ((size_t)SCAN_NB * 4 + 255) / 256 * 256;

    // --- CSR build ---
    hipMemsetAsync(row_cnt, 0, (size_t)NQ * 4, stream);
    hipMemsetAsync(row_fill, 0, (size_t)NQ * 4, stream);
    hist_kernel<<<(nnz + 255) / 256, 256, 0, stream>>>(rows, row_cnt, nnz);
    scanA_kernel<<<SCAN_NB, 256, 0, stream>>>(row_cnt, row_ofs, bsum, NQ);
    scanB_kernel<<<1, 64, 0, stream>>>(bsum);
    scanC_kernel<<<SCAN_NB, 256, 0, stream>>>(row_ofs, bsum, NQ, nnz);
    scatter_kernel<<<(nnz + 255) / 256, 256, 0, stream>>>(rows, cols, vals,
                                                          row_ofs, row_fill,
                                                          edge_cv, nnz);

    // --- side + scores + masks (one pass, no atomics) ---
    const int row_blocks = (NQ * 64 + 255) / 256;   // 4 waves/block
    side_scores_kernel<<<row_blocks, 256, 0, stream>>>(
        user_emb, item_emb, fc_w, fc_b, fcg_w, fcg_b,
        row_ofs, edge_cv, side32, mask);

    // --- propagation: 2 fused passes (all groups at once) ---
    layer1_kernel<<<row_blocks, 256, 0, stream>>>(row_ofs, edge_cv, mask,
                                                  side32, emb1, acc);
    layer2_kernel<<<row_blocks, 256, 0, stream>>>(row_ofs, edge_cv, mask,
                                                  emb1, acc);

    // --- gather + dot ---
    gamma_kernel<<<((size_t)B * 64 + 255) / 256, 256, 0, stream>>>(
        acc, users, items, out, B);
}

// Round 3
// 509.468 us; speedup vs baseline: 6.0918x; 1.9740x over previous
//
#include <hip/hip_runtime.h>
#include <hip/hip_bf16.h>

// LightGCN_27384711480190 — CSR + sampled-row-only layer2 + unrolled gathers.
#define NUQ 100000   // users
#define NIQ 50000    // items
#define NQ  150000   // N = NU + NI
#define DQ  64       // embedding dim (== wavefront)
#define GQ  4        // groups

#define SCAN_NB  ((NQ + 255) / 256)          // scan blocks
#define SCANB_PER ((SCAN_NB + 63) / 64)

// ---------------------------------------------------------------------------
// CSR build: histogram -> exclusive scan -> scatter.
__global__ void hist_kernel(const int* __restrict__ rows, int* __restrict__ cnt,
                            int nnz) {
    int e = blockIdx.x * blockDim.x + threadIdx.x;
    if (e < nnz) atomicAdd(&cnt[rows[e]], 1);
}

__global__ void scanA_kernel(const int* __restrict__ cnt, int* __restrict__ ofs,
                             int* __restrict__ bsum, int n) {
    int i = blockIdx.x * 256 + threadIdx.x;
    int v = (i < n) ? cnt[i] : 0;
    int lane = threadIdx.x & 63, w = threadIdx.x >> 6;
    int s = v;
    #pragma unroll
    for (int off = 1; off < 64; off <<= 1) {
        int t = __shfl_up(s, off, 64);
        if (lane >= off) s += t;
    }
    __shared__ int wsum[4];
    if (lane == 63) wsum[w] = s;
    __syncthreads();
    int add = 0;
    for (int k = 0; k < w; ++k) add += wsum[k];
    int incl = s + add;
    if (i < n) ofs[i] = incl - v;
    if (threadIdx.x == 255) bsum[blockIdx.x] = incl;
}

__global__ void scanB_kernel(int* __restrict__ bsum) {
    int lane = threadIdx.x;                 // single wave
    int base = lane * SCANB_PER;
    int local[SCANB_PER];
    int s = 0;
    #pragma unroll
    for (int k = 0; k < SCANB_PER; ++k) {
        int idx = base + k;
        int t = (idx < SCAN_NB) ? bsum[idx] : 0;
        local[k] = s;
        s += t;
    }
    int incl = s;
    #pragma unroll
    for (int off = 1; off < 64; off <<= 1) {
        int t = __shfl_up(incl, off, 64);
        if (lane >= off) incl += t;
    }
    int excl = incl - s;
    #pragma unroll
    for (int k = 0; k < SCANB_PER; ++k) {
        int idx = base + k;
        if (idx < SCAN_NB) bsum[idx] = excl + local[k];
    }
}

__global__ void scanC_kernel(int* __restrict__ ofs, const int* __restrict__ bsum,
                             int n, int nnz) {
    int i = blockIdx.x * 256 + threadIdx.x;
    if (i < n) ofs[i] += bsum[blockIdx.x];
    if (i == 0) ofs[n] = nnz;
}

__global__ void scatter_kernel(const int* __restrict__ rows,
                               const int* __restrict__ cols,
                               const float* __restrict__ vals,
                               const int* __restrict__ ofs,
                               int* __restrict__ fill,
                               uint2* __restrict__ edge_cv, int nnz) {
    int e = blockIdx.x * blockDim.x + threadIdx.x;
    if (e >= nnz) return;
    int r = rows[e];
    int pos = ofs[r] + atomicAdd(&fill[r], 1);
    edge_cv[pos] = make_uint2((unsigned)cols[e], __float_as_uint(vals[e]));
}

// Mark nodes whose layer-1 planes are ever read: sampled rows + their neighbors.
__global__ void mark_needed(const int* __restrict__ users,
                            const int* __restrict__ items,
                            const int* __restrict__ ofs,
                            const uint2* __restrict__ edge_cv,
                            unsigned char* __restrict__ needed, int B) {
    int wid  = (int)(((size_t)blockIdx.x * blockDim.x + threadIdx.x) >> 6);
    int lane = threadIdx.x & 63;
    if (wid >= 2 * B) return;
    int r = (wid < B) ? users[wid] : (NUQ + items[wid - B]);
    if (lane == 0) needed[r] = 1;
    int beg = ofs[r], end = ofs[r + 1];
    for (int i = beg + lane; i < end; i += 64) needed[(int)edge_cv[i].x] = 1;
}

// ---------------------------------------------------------------------------
// Fused: side row (f64, unrolled gathers) + FC/leaky/FC_g/argmax mask.
__global__ void side_scores_kernel(const float* __restrict__ user_emb,
                                   const float* __restrict__ item_emb,
                                   const float* __restrict__ fc_w,
                                   const float* __restrict__ fc_b,
                                   const float* __restrict__ fcg_w,
                                   const float* __restrict__ fcg_b,
                                   const int* __restrict__ ofs,
                                   const uint2* __restrict__ edge_cv,
                                   float* __restrict__ side32,
                                   unsigned int* __restrict__ mask) {
    int wid  = (int)(((size_t)blockIdx.x * blockDim.x + threadIdx.x) >> 6);
    int lane = threadIdx.x & 63;
    if (wid >= NQ) return;
    int r = wid;
    int beg = ofs[r], end = ofs[r + 1];
    double a = 0.0;
    int i = beg;
    for (; i + 3 < end; i += 4) {
        uint2 cv0 = edge_cv[i], cv1 = edge_cv[i + 1];
        uint2 cv2 = edge_cv[i + 2], cv3 = edge_cv[i + 3];
        int c0 = (int)cv0.x, c1 = (int)cv1.x, c2 = (int)cv2.x, c3 = (int)cv3.x;
        const float* p0 = (c0 < NUQ) ? user_emb + (size_t)c0 * DQ : item_emb + (size_t)(c0 - NUQ) * DQ;
        const float* p1 = (c1 < NUQ) ? user_emb + (size_t)c1 * DQ : item_emb + (size_t)(c1 - NUQ) * DQ;
        const float* p2 = (c2 < NUQ) ? user_emb + (size_t)c2 * DQ : item_emb + (size_t)(c2 - NUQ) * DQ;
        const float* p3 = (c3 < NUQ) ? user_emb + (size_t)c3 * DQ : item_emb + (size_t)(c3 - NUQ) * DQ;
        float f0 = p0[lane], f1 = p1[lane], f2 = p2[lane], f3 = p3[lane];
        a += (double)__uint_as_float(cv0.y) * (double)f0;
        a += (double)__uint_as_float(cv1.y) * (double)f1;
        a += (double)__uint_as_float(cv2.y) * (double)f2;
        a += (double)__uint_as_float(cv3.y) * (double)f3;
    }
    for (; i < end; ++i) {
        uint2 cv = edge_cv[i];
        int c = (int)cv.x;
        const float* p = (c < NUQ) ? user_emb + (size_t)c * DQ : item_emb + (size_t)(c - NUQ) * DQ;
        a += (double)__uint_as_float(cv.y) * (double)p[lane];
    }
    side32[(size_t)r * DQ + lane] = (float)a;

    if (r >= NUQ) {                       // items: all groups
        if (lane == 0) mask[r] = 0xFu;
        return;
    }
    // scores in f64 (argmax decision robustness vs np reference)
    double x = (double)user_emb[(size_t)r * DQ + lane] + a;
    double t = (double)fc_b[lane];
    #pragma unroll 16
    for (int k = 0; k < DQ; ++k) {
        double xk = __shfl(x, k, 64);
        t += xk * (double)fc_w[k * DQ + lane];
    }
    t = (t > 0.0) ? t : 0.01 * t;         // leaky_relu
    double s[GQ];
    #pragma unroll
    for (int g = 0; g < GQ; ++g) {
        double v2 = t * (double)fcg_w[lane * GQ + g];
        #pragma unroll
        for (int off = 32; off > 0; off >>= 1) v2 += __shfl_xor(v2, off, 64);
        s[g] = v2 + (double)fcg_b[g];
    }
    double m = fmax(fmax(s[0], s[1]), fmax(s[2], s[3]));
    unsigned bits = 0;
    #pragma unroll
    for (int g = 0; g < GQ; ++g) if (s[g] == m) bits |= (1u << g);
    if (lane == 0) mask[r] = bits;
}

// ---------------------------------------------------------------------------
// Layer 1, only for needed rows. Writes 4 group planes + sum plane (plane 4).
__global__ void layer1_kernel(const int* __restrict__ ofs,
                              const uint2* __restrict__ edge_cv,
                              const unsigned int* __restrict__ mask,
                              const unsigned char* __restrict__ needed,
                              const float* __restrict__ side32,
                              float* __restrict__ emb5) {  // [5][N][64]
    int wid  = (int)(((size_t)blockIdx.x * blockDim.x + threadIdx.x) >> 6);
    int lane = threadIdx.x & 63;
    if (wid >= NQ) return;
    int r = wid;
    if (!needed[r]) return;
    unsigned mr = mask[r];
    int beg = ofs[r], end = ofs[r + 1];
    float a0 = 0.f, a1 = 0.f, a2 = 0.f, a3 = 0.f;
    int i = beg;
    for (; i + 3 < end; i += 4) {
        uint2 cv0 = edge_cv[i], cv1 = edge_cv[i + 1];
        uint2 cv2 = edge_cv[i + 2], cv3 = edge_cv[i + 3];
        int c0 = (int)cv0.x, c1 = (int)cv1.x, c2 = (int)cv2.x, c3 = (int)cv3.x;
        unsigned m0 = mr & mask[c0], m1 = mr & mask[c1];
        unsigned m2 = mr & mask[c2], m3 = mr & mask[c3];
        float s0 = side32[(size_t)c0 * DQ + lane];
        float s1 = side32[(size_t)c1 * DQ + lane];
        float s2 = side32[(size_t)c2 * DQ + lane];
        float s3 = side32[(size_t)c3 * DQ + lane];
        float w0 = __uint_as_float(cv0.y) * s0;
        float w1 = __uint_as_float(cv1.y) * s1;
        float w2 = __uint_as_float(cv2.y) * s2;
        float w3 = __uint_as_float(cv3.y) * s3;
        a0 += (m0 & 1u) ? w0 : 0.f;  a1 += (m0 & 2u) ? w0 : 0.f;
        a2 += (m0 & 4u) ? w0 : 0.f;  a3 += (m0 & 8u) ? w0 : 0.f;
        a0 += (m1 & 1u) ? w1 : 0.f;  a1 += (m1 & 2u) ? w1 : 0.f;
        a2 += (m1 & 4u) ? w1 : 0.f;  a3 += (m1 & 8u) ? w1 : 0.f;
        a0 += (m2 & 1u) ? w2 : 0.f;  a1 += (m2 & 2u) ? w2 : 0.f;
        a2 += (m2 & 4u) ? w2 : 0.f;  a3 += (m2 & 8u) ? w2 : 0.f;
        a0 += (m3 & 1u) ? w3 : 0.f;  a1 += (m3 & 2u) ? w3 : 0.f;
        a2 += (m3 & 4u) ? w3 : 0.f;  a3 += (m3 & 8u) ? w3 : 0.f;
    }
    for (; i < end; ++i) {
        uint2 cv = edge_cv[i];
        int c = (int)cv.x;
        unsigned mb = mr & mask[c];
        float w = __uint_as_float(cv.y) * side32[(size_t)c * DQ + lane];
        a0 += (mb & 1u) ? w : 0.f;  a1 += (mb & 2u) ? w : 0.f;
        a2 += (mb & 4u) ? w : 0.f;  a3 += (mb & 8u) ? w : 0.f;
    }
    const size_t ND = (size_t)NQ * DQ;
    size_t o = (size_t)r * DQ + lane;
    emb5[o]          = a0;
    emb5[ND + o]     = a1;
    emb5[2 * ND + o] = a2;
    emb5[3 * ND + o] = a3;
    emb5[4 * ND + o] = a0 + a1 + a2 + a3;   // sum plane
}

// ---------------------------------------------------------------------------
// Fused layer2 + gamma, sampled rows only.
// final[r] = 0.2*(4*side[r] + sumplane[r] + l2(r)); gamma = dot(finalU, finalI).
__device__ __forceinline__ float l2_row(int r, int lane,
                                        const int* __restrict__ ofs,
                                        const uint2* __restrict__ edge_cv,
                                        const unsigned int* __restrict__ mask,
                                        const float* __restrict__ emb5) {
    const size_t ND = (size_t)NQ * DQ;
    unsigned mr = mask[r];
    int beg = ofs[r], end = ofs[r + 1];
    float sum = 0.f;
    for (int i = beg; i < end; ++i) {
        uint2 cv = edge_cv[i];
        int c = (int)cv.x;
        unsigned mb = mr & mask[c];
        if (!mb) continue;
        float v = __uint_as_float(cv.y);
        size_t co = (size_t)c * DQ + lane;
        if (mb == 0xFu) {
            sum += v * emb5[4 * ND + co];
        } else if ((mb & (mb - 1)) == 0) {
            int p = __ffs(mb) - 1;
            sum += v * emb5[(size_t)p * ND + co];
        } else {  // rare ties (popcount 2-3)
            #pragma unroll
            for (int g = 0; g < GQ; ++g)
                if ((mb >> g) & 1u) sum += v * emb5[(size_t)g * ND + co];
        }
    }
    return sum;
}

__global__ void gamma_kernel(const int* __restrict__ ofs,
                             const uint2* __restrict__ edge_cv,
                             const unsigned int* __restrict__ mask,
                             const float* __restrict__ side32,
                             const float* __restrict__ emb5,
                             const int* __restrict__ users,
                             const int* __restrict__ items,
                             float* __restrict__ out, int B) {
    int wid  = (int)(((size_t)blockIdx.x * blockDim.x + threadIdx.x) >> 6);
    int lane = threadIdx.x & 63;
    if (wid >= B) return;
    const size_t ND = (size_t)NQ * DQ;
    int u  = users[wid];
    int it = NUQ + items[wid];
    size_t uo = (size_t)u * DQ + lane;
    size_t io = (size_t)it * DQ + lane;
    float fu = 4.f * side32[uo] + emb5[4 * ND + uo]
             + l2_row(u, lane, ofs, edge_cv, mask, emb5);
    float fi = 4.f * side32[io] + emb5[4 * ND + io]
             + l2_row(it, lane, ofs, edge_cv, mask, emb5);
    float p = fu * fi;
    #pragma unroll
    for (int off = 32; off > 0; off >>= 1) p += __shfl_xor(p, off, 64);
    if (lane == 0) out[wid] = 0.04f * p;   // 0.2^2
}

// ---------------------------------------------------------------------------
extern "C" void kernel_launch(void* const* d_in, const int* in_sizes, int n_in,
                              void* d_out, int out_size, void* d_ws, size_t ws_size,
                              hipStream_t stream) {
    const float* user_emb = (const float*)d_in[0];
    const float* item_emb = (const float*)d_in[1];
    const float* fc_w     = (const float*)d_in[2];
    const float* fc_b     = (const float*)d_in[3];
    const float* fcg_w    = (const float*)d_in[4];
    const float* fcg_b    = (const float*)d_in[5];
    const float* vals     = (const float*)d_in[6];
    const int*   rows     = (const int*)d_in[7];
    const int*   cols     = (const int*)d_in[8];
    const int*   users    = (const int*)d_in[9];
    const int*   items    = (const int*)d_in[10];
    const int nnz = in_sizes[6];
    const int B   = in_sizes[9];
    float* out = (float*)d_out;

    const size_t ND = (size_t)NQ * DQ;           // 9.6M floats

    char* ws = (char*)d_ws;
    size_t off = 0;
    float* emb5   = (float*)(ws + off); off += 5 * ND * sizeof(float);  // 192 MB
    float* side32 = (float*)(ws + off); off += ND * sizeof(float);      // 38.4 MB
    uint2* edge_cv = (uint2*)(ws + off); off += (size_t)nnz * 8;        // 16 MB
    int* row_ofs  = (int*)(ws + off); off += ((size_t)(NQ + 1) * 4 + 255) / 256 * 256;
    int* row_cnt  = (int*)(ws + off); off += ((size_t)NQ * 4 + 255) / 256 * 256;
    int* row_fill = (int*)(ws + off); off += ((size_t)NQ * 4 + 255) / 256 * 256;
    unsigned int* mask = (unsigned int*)(ws + off); off += ((size_t)NQ * 4 + 255) / 256 * 256;
    int* bsum     = (int*)(ws + off); off += ((size_t)SCAN_NB * 4 + 255) / 256 * 256;
    unsigned char* needed = (unsigned char*)(ws + off); off += ((size_t)NQ + 255) / 256 * 256;

    // --- CSR build ---
    hipMemsetAsync(row_cnt, 0, (size_t)NQ * 4, stream);
    hipMemsetAsync(row_fill, 0, (size_t)NQ * 4, stream);
    hipMemsetAsync(needed, 0, (size_t)NQ, stream);
    hist_kernel<<<(nnz + 255) / 256, 256, 0, stream>>>(rows, row_cnt, nnz);
    scanA_kernel<<<SCAN_NB, 256, 0, stream>>>(row_cnt, row_ofs, bsum, NQ);
    scanB_kernel<<<1, 64, 0, stream>>>(bsum);
    scanC_kernel<<<SCAN_NB, 256, 0, stream>>>(row_ofs, bsum, NQ, nnz);
    scatter_kernel<<<(nnz + 255) / 256, 256, 0, stream>>>(rows, cols, vals,
                                                          row_ofs, row_fill,
                                                          edge_cv, nnz);
    mark_needed<<<(2 * B * 64 + 255) / 256, 256, 0, stream>>>(
        users, items, row_ofs, edge_cv, needed, B);

    // --- side + scores + masks ---
    const int row_blocks = (NQ * 64 + 255) / 256;   // 4 waves/block
    side_scores_kernel<<<row_blocks, 256, 0, stream>>>(
        user_emb, item_emb, fc_w, fc_b, fcg_w, fcg_b,
        row_ofs, edge_cv, side32, mask);

    // --- layer 1 (needed rows only) ---
    layer1_kernel<<<row_blocks, 256, 0, stream>>>(row_ofs, edge_cv, mask,
                                                  needed, side32, emb5);

    // --- fused layer2 + gamma (sampled rows only) ---
    gamma_kernel<<<((size_t)B * 64 + 255) / 256, 256, 0, stream>>>(
        row_ofs, edge_cv, mask, side32, emb5, users, items, out, B);
}

// Round 4
// 461.014 us; speedup vs baseline: 6.7321x; 1.1051x over previous
//
#include <hip/hip_runtime.h>
#include <hip/hip_bf16.h>

// LightGCN_27384711480190 — r4: lane-parallel edge fetch + f32 hot path with
// f64 margin-fallback for argmax robustness.
#define NUQ 100000   // users
#define NIQ 50000    // items
#define NQ  150000   // N = NU + NI
#define DQ  64       // embedding dim (== wavefront)
#define GQ  4        // groups
#define EPSM 2e-3f   // f32 argmax safety margin (f32 score err ~1e-5)

#define SCAN_NB  ((NQ + 255) / 256)
#define SCANB_PER ((SCAN_NB + 63) / 64)

// ---------------------------------------------------------------------------
// CSR build: histogram -> exclusive scan -> scatter.
__global__ void hist_kernel(const int* __restrict__ rows, int* __restrict__ cnt,
                            int nnz) {
    int e = blockIdx.x * blockDim.x + threadIdx.x;
    if (e < nnz) atomicAdd(&cnt[rows[e]], 1);
}

__global__ void scanA_kernel(const int* __restrict__ cnt, int* __restrict__ ofs,
                             int* __restrict__ bsum, int n) {
    int i = blockIdx.x * 256 + threadIdx.x;
    int v = (i < n) ? cnt[i] : 0;
    int lane = threadIdx.x & 63, w = threadIdx.x >> 6;
    int s = v;
    #pragma unroll
    for (int off = 1; off < 64; off <<= 1) {
        int t = __shfl_up(s, off, 64);
        if (lane >= off) s += t;
    }
    __shared__ int wsum[4];
    if (lane == 63) wsum[w] = s;
    __syncthreads();
    int add = 0;
    for (int k = 0; k < w; ++k) add += wsum[k];
    int incl = s + add;
    if (i < n) ofs[i] = incl - v;
    if (threadIdx.x == 255) bsum[blockIdx.x] = incl;
}

__global__ void scanB_kernel(int* __restrict__ bsum) {
    int lane = threadIdx.x;                 // single wave
    int base = lane * SCANB_PER;
    int local[SCANB_PER];
    int s = 0;
    #pragma unroll
    for (int k = 0; k < SCANB_PER; ++k) {
        int idx = base + k;
        int t = (idx < SCAN_NB) ? bsum[idx] : 0;
        local[k] = s;
        s += t;
    }
    int incl = s;
    #pragma unroll
    for (int off = 1; off < 64; off <<= 1) {
        int t = __shfl_up(incl, off, 64);
        if (lane >= off) incl += t;
    }
    int excl = incl - s;
    #pragma unroll
    for (int k = 0; k < SCANB_PER; ++k) {
        int idx = base + k;
        if (idx < SCAN_NB) bsum[idx] = excl + local[k];
    }
}

__global__ void scanC_kernel(int* __restrict__ ofs, const int* __restrict__ bsum,
                             int n, int nnz) {
    int i = blockIdx.x * 256 + threadIdx.x;
    if (i < n) ofs[i] += bsum[blockIdx.x];
    if (i == 0) ofs[n] = nnz;
}

__global__ void scatter_kernel(const int* __restrict__ rows,
                               const int* __restrict__ cols,
                               const float* __restrict__ vals,
                               const int* __restrict__ ofs,
                               int* __restrict__ fill,
                               uint2* __restrict__ edge_cv, int nnz) {
    int e = blockIdx.x * blockDim.x + threadIdx.x;
    if (e >= nnz) return;
    int r = rows[e];
    int pos = ofs[r] + atomicAdd(&fill[r], 1);
    edge_cv[pos] = make_uint2((unsigned)cols[e], __float_as_uint(vals[e]));
}

// Mark nodes whose layer-1 planes are ever read: sampled rows + their neighbors.
__global__ void mark_needed(const int* __restrict__ users,
                            const int* __restrict__ items,
                            const int* __restrict__ ofs,
                            const uint2* __restrict__ edge_cv,
                            unsigned char* __restrict__ needed, int B) {
    int wid  = (int)(((size_t)blockIdx.x * blockDim.x + threadIdx.x) >> 6);
    int lane = threadIdx.x & 63;
    if (wid >= 2 * B) return;
    int r = (wid < B) ? users[wid] : (NUQ + items[wid - B]);
    if (lane == 0) needed[r] = 1;
    int beg = ofs[r], end = ofs[r + 1];
    for (int i = beg + lane; i < end; i += 64) needed[(int)edge_cv[i].x] = 1;
}

// ---------------------------------------------------------------------------
// Fused side + scores, f32 with margin check. Lane-parallel edge fetch:
// one coalesced load of <=64 edges, shfl-broadcast, independent gathers.
__global__ void side_scores_kernel(const float* __restrict__ user_emb,
                                   const float* __restrict__ item_emb,
                                   const float* __restrict__ fc_w,
                                   const float* __restrict__ fc_b,
                                   const float* __restrict__ fcg_w,
                                   const float* __restrict__ fcg_b,
                                   const int* __restrict__ ofs,
                                   const uint2* __restrict__ edge_cv,
                                   float* __restrict__ side32,
                                   unsigned char* __restrict__ mask8,
                                   unsigned char* __restrict__ risky) {
    int wid  = (int)(((size_t)blockIdx.x * blockDim.x + threadIdx.x) >> 6);
    int lane = threadIdx.x & 63;
    if (wid >= NQ) return;
    int r = wid;
    int beg = ofs[r], end = ofs[r + 1];
    const float* ib = item_emb - (size_t)NUQ * DQ;   // ib + c*DQ valid for c>=NUQ
    float a = 0.f;
    for (int base = beg; base < end; base += 64) {
        int n = end - base; if (n > 64) n = 64;
        int n1 = n - 1;
        uint2 cv = edge_cv[base + (lane < n ? lane : n1)];
        int   cc = (int)cv.x;
        float vv = __uint_as_float(cv.y);
        for (int e = 0; e < n; e += 4) {
            int i1 = (e + 1 > n1) ? n1 : e + 1;
            int i2 = (e + 2 > n1) ? n1 : e + 2;
            int i3 = (e + 3 > n1) ? n1 : e + 3;
            int c0 = __shfl(cc, e, 64),  c1 = __shfl(cc, i1, 64);
            int c2 = __shfl(cc, i2, 64), c3 = __shfl(cc, i3, 64);
            float v0 = __shfl(vv, e, 64);
            float v1 = __shfl(vv, i1, 64); if (e + 1 > n1) v1 = 0.f;
            float v2 = __shfl(vv, i2, 64); if (e + 2 > n1) v2 = 0.f;
            float v3 = __shfl(vv, i3, 64); if (e + 3 > n1) v3 = 0.f;
            const float* p0 = ((c0 < NUQ) ? user_emb : ib) + (size_t)c0 * DQ;
            const float* p1 = ((c1 < NUQ) ? user_emb : ib) + (size_t)c1 * DQ;
            const float* p2 = ((c2 < NUQ) ? user_emb : ib) + (size_t)c2 * DQ;
            const float* p3 = ((c3 < NUQ) ? user_emb : ib) + (size_t)c3 * DQ;
            float f0 = p0[lane], f1 = p1[lane], f2 = p2[lane], f3 = p3[lane];
            a += v0 * f0; a += v1 * f1; a += v2 * f2; a += v3 * f3;
        }
    }
    side32[(size_t)r * DQ + lane] = a;

    if (r >= NUQ) {                       // items: all groups
        if (lane == 0) mask8[r] = 0xFu;
        return;
    }
    // f32 scores + margin check
    float x = user_emb[(size_t)r * DQ + lane] + a;
    float t = fc_b[lane];
    #pragma unroll 16
    for (int k = 0; k < DQ; ++k)
        t += __shfl(x, k, 64) * fc_w[k * DQ + lane];
    t = (t > 0.f) ? t : 0.01f * t;        // leaky_relu
    float sg[GQ];
    #pragma unroll
    for (int g = 0; g < GQ; ++g) {
        float v2 = t * fcg_w[lane * GQ + g];
        #pragma unroll
        for (int off = 32; off > 0; off >>= 1) v2 += __shfl_xor(v2, off, 64);
        sg[g] = v2 + fcg_b[g];
    }
    float m = fmaxf(fmaxf(sg[0], sg[1]), fmaxf(sg[2], sg[3]));
    int cnt = 0, arg = 0;
    #pragma unroll
    for (int g = 0; g < GQ; ++g)
        if (m - sg[g] < EPSM) { ++cnt; arg = g; }
    if (lane == 0) {
        if (cnt > 1) risky[r] = 1;                     // defer to f64 fixup
        else         mask8[r] = (unsigned char)(1u << arg);
    }
}

// f64 fixup for near-tie rows (expected: a handful).
__global__ void fix_risky_kernel(const float* __restrict__ user_emb,
                                 const float* __restrict__ item_emb,
                                 const float* __restrict__ fc_w,
                                 const float* __restrict__ fc_b,
                                 const float* __restrict__ fcg_w,
                                 const float* __restrict__ fcg_b,
                                 const int* __restrict__ ofs,
                                 const uint2* __restrict__ edge_cv,
                                 const unsigned char* __restrict__ risky,
                                 unsigned char* __restrict__ mask8) {
    int wid  = (int)(((size_t)blockIdx.x * blockDim.x + threadIdx.x) >> 6);
    int lane = threadIdx.x & 63;
    if (wid >= NUQ) return;
    int r = wid;
    if (!risky[r]) return;
    const float* ib = item_emb - (size_t)NUQ * DQ;
    int beg = ofs[r], end = ofs[r + 1];
    double a = 0.0;
    for (int i = beg; i < end; ++i) {
        uint2 cv = edge_cv[i];
        int c = (int)cv.x;
        const float* p = ((c < NUQ) ? user_emb : ib) + (size_t)c * DQ;
        a += (double)__uint_as_float(cv.y) * (double)p[lane];
    }
    double x = (double)user_emb[(size_t)r * DQ + lane] + a;
    double t = (double)fc_b[lane];
    for (int k = 0; k < DQ; ++k)
        t += __shfl(x, k, 64) * (double)fc_w[k * DQ + lane];
    t = (t > 0.0) ? t : 0.01 * t;
    double sg[GQ];
    #pragma unroll
    for (int g = 0; g < GQ; ++g) {
        double v2 = t * (double)fcg_w[lane * GQ + g];
        #pragma unroll
        for (int off = 32; off > 0; off >>= 1) v2 += __shfl_xor(v2, off, 64);
        sg[g] = v2 + (double)fcg_b[g];
    }
    double m = fmax(fmax(sg[0], sg[1]), fmax(sg[2], sg[3]));
    unsigned bits = 0;
    #pragma unroll
    for (int g = 0; g < GQ; ++g) if (sg[g] == m) bits |= (1u << g);
    if (lane == 0) mask8[r] = (unsigned char)bits;
}

// ---------------------------------------------------------------------------
// Layer 1 for needed rows. emb4 layout [N][4][64]. Single-group rows write
// only their own plane (the only one ever read downstream).
__global__ void layer1_kernel(const int* __restrict__ ofs,
                              const uint2* __restrict__ edge_cv,
                              const unsigned char* __restrict__ mask8,
                              const unsigned char* __restrict__ needed,
                              const float* __restrict__ side32,
                              float* __restrict__ emb4) {
    int wid  = (int)(((size_t)blockIdx.x * blockDim.x + threadIdx.x) >> 6);
    int lane = threadIdx.x & 63;
    if (wid >= NQ) return;
    int r = wid;
    if (!needed[r]) return;
    unsigned mr = mask8[r];
    int beg = ofs[r], end = ofs[r + 1];
    bool single = (mr & (mr - 1u)) == 0u;

    if (single) {
        float a = 0.f;
        for (int base = beg; base < end; base += 64) {
            int n = end - base; if (n > 64) n = 64;
            int n1 = n - 1;
            uint2 cv = edge_cv[base + (lane < n ? lane : n1)];
            int   cc = (int)cv.x;
            float vv = __uint_as_float(cv.y);
            int pack = cc | ((int)(mr & (unsigned)mask8[cc]) << 20);
            for (int e = 0; e < n; e += 4) {
                int i1 = (e + 1 > n1) ? n1 : e + 1;
                int i2 = (e + 2 > n1) ? n1 : e + 2;
                int i3 = (e + 3 > n1) ? n1 : e + 3;
                int w0 = __shfl(pack, e, 64),  w1 = __shfl(pack, i1, 64);
                int w2 = __shfl(pack, i2, 64), w3 = __shfl(pack, i3, 64);
                if ((((w0 | w1 | w2 | w3) >> 20) & 0xF) == 0) continue;
                float v0 = __shfl(vv, e, 64);  if (!(w0 >> 20)) v0 = 0.f;
                float v1 = __shfl(vv, i1, 64); if (e + 1 > n1 || !(w1 >> 20)) v1 = 0.f;
                float v2 = __shfl(vv, i2, 64); if (e + 2 > n1 || !(w2 >> 20)) v2 = 0.f;
                float v3 = __shfl(vv, i3, 64); if (e + 3 > n1 || !(w3 >> 20)) v3 = 0.f;
                float f0 = side32[(size_t)(w0 & 0xFFFFF) * DQ + lane];
                float f1 = side32[(size_t)(w1 & 0xFFFFF) * DQ + lane];
                float f2 = side32[(size_t)(w2 & 0xFFFFF) * DQ + lane];
                float f3 = side32[(size_t)(w3 & 0xFFFFF) * DQ + lane];
                a += v0 * f0; a += v1 * f1; a += v2 * f2; a += v3 * f3;
            }
        }
        int p = __ffs((int)mr) - 1;
        emb4[((size_t)r * GQ + p) * DQ + lane] = a;
    } else {
        float a0 = 0.f, a1 = 0.f, a2 = 0.f, a3 = 0.f;
        for (int base = beg; base < end; base += 64) {
            int n = end - base; if (n > 64) n = 64;
            int n1 = n - 1;
            uint2 cv = edge_cv[base + (lane < n ? lane : n1)];
            int   cc = (int)cv.x;
            float vv = __uint_as_float(cv.y);
            int pack = cc | ((int)(mr & (unsigned)mask8[cc]) << 20);
            for (int e = 0; e < n; e += 4) {
                int i1 = (e + 1 > n1) ? n1 : e + 1;
                int i2 = (e + 2 > n1) ? n1 : e + 2;
                int i3 = (e + 3 > n1) ? n1 : e + 3;
                int w0 = __shfl(pack, e, 64),  w1 = __shfl(pack, i1, 64);
                int w2 = __shfl(pack, i2, 64), w3 = __shfl(pack, i3, 64);
                float v0 = __shfl(vv, e, 64);
                float v1 = __shfl(vv, i1, 64); if (e + 1 > n1) v1 = 0.f;
                float v2 = __shfl(vv, i2, 64); if (e + 2 > n1) v2 = 0.f;
                float v3 = __shfl(vv, i3, 64); if (e + 3 > n1) v3 = 0.f;
                float f0 = v0 * side32[(size_t)(w0 & 0xFFFFF) * DQ + lane];
                float f1 = v1 * side32[(size_t)(w1 & 0xFFFFF) * DQ + lane];
                float f2 = v2 * side32[(size_t)(w2 & 0xFFFFF) * DQ + lane];
                float f3 = v3 * side32[(size_t)(w3 & 0xFFFFF) * DQ + lane];
                unsigned m0 = (unsigned)w0 >> 20, m1 = (unsigned)w1 >> 20;
                unsigned m2 = (unsigned)w2 >> 20, m3 = (unsigned)w3 >> 20;
                a0 += (m0 & 1u) ? f0 : 0.f;  a1 += (m0 & 2u) ? f0 : 0.f;
                a2 += (m0 & 4u) ? f0 : 0.f;  a3 += (m0 & 8u) ? f0 : 0.f;
                a0 += (m1 & 1u) ? f1 : 0.f;  a1 += (m1 & 2u) ? f1 : 0.f;
                a2 += (m1 & 4u) ? f1 : 0.f;  a3 += (m1 & 8u) ? f1 : 0.f;
                a0 += (m2 & 1u) ? f2 : 0.f;  a1 += (m2 & 2u) ? f2 : 0.f;
                a2 += (m2 & 4u) ? f2 : 0.f;  a3 += (m2 & 8u) ? f2 : 0.f;
                a0 += (m3 & 1u) ? f3 : 0.f;  a1 += (m3 & 2u) ? f3 : 0.f;
                a2 += (m3 & 4u) ? f3 : 0.f;  a3 += (m3 & 8u) ? f3 : 0.f;
            }
        }
        size_t o = (size_t)r * GQ * DQ + lane;
        emb4[o]          = a0;
        emb4[o + DQ]     = a1;
        emb4[o + 2 * DQ] = a2;
        emb4[o + 3 * DQ] = a3;
    }
}

// ---------------------------------------------------------------------------
// Fused layer2 + gamma, sampled rows only.
__device__ __forceinline__ float l2_row(int r, int lane, unsigned mr,
                                        const int* __restrict__ ofs,
                                        const uint2* __restrict__ edge_cv,
                                        const unsigned char* __restrict__ mask8,
                                        const float* __restrict__ emb4) {
    float sum = 0.f;
    int beg = ofs[r], end = ofs[r + 1];
    for (int base = beg; base < end; base += 64) {
        int n = end - base; if (n > 64) n = 64;
        int n1 = n - 1;
        uint2 cv = edge_cv[base + (lane < n ? lane : n1)];
        int   cc = (int)cv.x;
        float vv = __uint_as_float(cv.y);
        int pack = cc | ((int)(mr & (unsigned)mask8[cc]) << 20);
        for (int e = 0; e < n; ++e) {
            int w = __shfl(pack, e, 64);
            unsigned mb = ((unsigned)w >> 20) & 0xFu;
            if (!mb) continue;
            float v = __shfl(vv, e, 64);
            size_t co = (size_t)(w & 0xFFFFF) * (GQ * DQ) + lane;
            if (mb == 0xFu) {
                sum += v * (emb4[co] + emb4[co + DQ] + emb4[co + 2 * DQ] + emb4[co + 3 * DQ]);
            } else if ((mb & (mb - 1u)) == 0u) {
                sum += v * emb4[co + ((__ffs((int)mb) - 1) << 6)];
            } else {
                #pragma unroll
                for (int g = 0; g < GQ; ++g)
                    if ((mb >> g) & 1u) sum += v * emb4[co + (g << 6)];
            }
        }
    }
    return sum;
}

__global__ void gamma_kernel(const int* __restrict__ ofs,
                             const uint2* __restrict__ edge_cv,
                             const unsigned char* __restrict__ mask8,
                             const float* __restrict__ side32,
                             const float* __restrict__ emb4,
                             const int* __restrict__ users,
                             const int* __restrict__ items,
                             float* __restrict__ out, int B) {
    int wid  = (int)(((size_t)blockIdx.x * blockDim.x + threadIdx.x) >> 6);
    int lane = threadIdx.x & 63;
    if (wid >= B) return;
    int u  = users[wid];
    int it = NUQ + items[wid];
    unsigned mu = mask8[u];
    size_t uo = (size_t)u * GQ * DQ + lane;
    size_t io = (size_t)it * GQ * DQ + lane;
    float baseu = 0.f;
    #pragma unroll
    for (int g = 0; g < GQ; ++g)
        if ((mu >> g) & 1u) baseu += emb4[uo + (g << 6)];
    float basei = emb4[io] + emb4[io + DQ] + emb4[io + 2 * DQ] + emb4[io + 3 * DQ];
    float fu = 4.f * side32[(size_t)u * DQ + lane] + baseu
             + l2_row(u, lane, mu, ofs, edge_cv, mask8, emb4);
    float fi = 4.f * side32[(size_t)it * DQ + lane] + basei
             + l2_row(it, lane, 0xFu, ofs, edge_cv, mask8, emb4);
    float p = fu * fi;
    #pragma unroll
    for (int off = 32; off > 0; off >>= 1) p += __shfl_xor(p, off, 64);
    if (lane == 0) out[wid] = 0.04f * p;   // 0.2^2
}

// ---------------------------------------------------------------------------
extern "C" void kernel_launch(void* const* d_in, const int* in_sizes, int n_in,
                              void* d_out, int out_size, void* d_ws, size_t ws_size,
                              hipStream_t stream) {
    const float* user_emb = (const float*)d_in[0];
    const float* item_emb = (const float*)d_in[1];
    const float* fc_w     = (const float*)d_in[2];
    const float* fc_b     = (const float*)d_in[3];
    const float* fcg_w    = (const float*)d_in[4];
    const float* fcg_b    = (const float*)d_in[5];
    const float* vals     = (const float*)d_in[6];
    const int*   rows     = (const int*)d_in[7];
    const int*   cols     = (const int*)d_in[8];
    const int*   users    = (const int*)d_in[9];
    const int*   items    = (const int*)d_in[10];
    const int nnz = in_sizes[6];
    const int B   = in_sizes[9];
    float* out = (float*)d_out;

    const size_t ND = (size_t)NQ * DQ;

    char* ws = (char*)d_ws;
    size_t off = 0;
    float* emb4   = (float*)(ws + off); off += 4 * ND * sizeof(float);  // 153.6 MB
    float* side32 = (float*)(ws + off); off += ND * sizeof(float);      //  38.4 MB
    uint2* edge_cv = (uint2*)(ws + off); off += (size_t)nnz * 8;        //  16.0 MB
    int* row_ofs  = (int*)(ws + off); off += ((size_t)(NQ + 1) * 4 + 255) / 256 * 256;
    int* row_cnt  = (int*)(ws + off); off += ((size_t)NQ * 4 + 255) / 256 * 256;
    int* row_fill = (int*)(ws + off); off += ((size_t)NQ * 4 + 255) / 256 * 256;
    int* bsum     = (int*)(ws + off); off += ((size_t)SCAN_NB * 4 + 255) / 256 * 256;
    unsigned char* mask8  = (unsigned char*)(ws + off); off += ((size_t)NQ + 255) / 256 * 256;
    unsigned char* needed = (unsigned char*)(ws + off); off += ((size_t)NQ + 255) / 256 * 256;
    unsigned char* risky  = (unsigned char*)(ws + off); off += ((size_t)NUQ + 255) / 256 * 256;

    // --- CSR build ---
    hipMemsetAsync(row_cnt, 0, (size_t)NQ * 4, stream);
    hipMemsetAsync(row_fill, 0, (size_t)NQ * 4, stream);
    hipMemsetAsync(needed, 0, (size_t)NQ, stream);
    hipMemsetAsync(risky, 0, (size_t)NUQ, stream);
    hist_kernel<<<(nnz + 255) / 256, 256, 0, stream>>>(rows, row_cnt, nnz);
    scanA_kernel<<<SCAN_NB, 256, 0, stream>>>(row_cnt, row_ofs, bsum, NQ);
    scanB_kernel<<<1, 64, 0, stream>>>(bsum);
    scanC_kernel<<<SCAN_NB, 256, 0, stream>>>(row_ofs, bsum, NQ, nnz);
    scatter_kernel<<<(nnz + 255) / 256, 256, 0, stream>>>(rows, cols, vals,
                                                          row_ofs, row_fill,
                                                          edge_cv, nnz);
    mark_needed<<<(2 * B * 64 + 255) / 256, 256, 0, stream>>>(
        users, items, row_ofs, edge_cv, needed, B);

    // --- side + scores + masks (f32, margin-checked) ---
    const int row_blocks = (NQ * 64 + 255) / 256;   // 4 waves/block
    side_scores_kernel<<<row_blocks, 256, 0, stream>>>(
        user_emb, item_emb, fc_w, fc_b, fcg_w, fcg_b,
        row_ofs, edge_cv, side32, mask8, risky);
    fix_risky_kernel<<<(NUQ * 64 + 255) / 256, 256, 0, stream>>>(
        user_emb, item_emb, fc_w, fc_b, fcg_w, fcg_b,
        row_ofs, edge_cv, risky, mask8);

    // --- layer 1 (needed rows only) ---
    layer1_kernel<<<row_blocks, 256, 0, stream>>>(row_ofs, edge_cv, mask8,
                                                  needed, side32, emb4);

    // --- fused layer2 + gamma (sampled rows only) ---
    gamma_kernel<<<((size_t)B * 64 + 255) / 256, 256, 0, stream>>>(
        row_ofs, edge_cv, mask8, side32, emb4, users, items, out, B);
}